// Round 5
// baseline (296.725 us; speedup 1.0000x reference)
//
#include <hip/hip_runtime.h>
#include <hip/hip_fp16.h>

// Problem constants (fixed by the reference file)
#define NN 50000     // nodes
#define NE 800000    // edges
#define HD 64        // feature dim (in and hidden)
#define NG 512       // graphs
#define NBK 196      // node buckets: node >> 8, max 49999>>8 = 195
#define NBL 196      // edge blocks of 4096: ceil(NE/4096)
#define GEMM_BLOCKS 3125        // NN/16

// Math: with h' = dinv*h (fp16):
//   o[c]   = dinv[c] * (sum_src h'[src] + h'[c]) + b          (layer output)
//   h'next = dinv * (relu(o) @ Wnext)                          (fused GEMM)
// R24: direct-atomic CSR build. dinv is computed BEFORE gemm1 (hist+nscan),
// so gemm1 writes h16 already scaled (single fp16 rounding — R19-verified).
// Deleted: packed[] (6.4 MB traffic), csr_build kernel (incl. 12.8 MB h16
// rescale pass), one scan kernel. Edge order within a row is atomic-
// nondeterministic — same class as the old LDS-cursor scheme; invisible at
// the harness's bf16-granular compare (absmax 0.0 through R23).
//
// Gather body is R15/R21's proven shape (46.5-47.5 µs; ~12 variants tried):
// node-per-wave, scalar esrc stream, unmasked 8-edge batches + ONE masked
// batch, independent loads hoisted. DO NOT TOUCH:
//  - R20: int t[32] preload -> scratch spill (+25.6MB writes), 2x slower.
//  - R22: h2x2 8B-aggregate loads -> 8B/thread scratch spill, 2x slower.
//    FETCH 35MB ~= compulsory floor (each XCD reads ~2 rows/line of the
//    6.4MB h16) -> gather is at its random-fabric roofline.
// R23: gemm1 GEMM half: W column in VGPRs + wave-uniform broadcast float4
// LDS reads (was LDS-issue-bound). k-ascending FMA order -> bit-identical.

// ---------------------------------------------------------------------------
// hist: in-degree via global atomics + per-block LDS bucket hist -> bsum
// (bsum[k] = #edges with col in [k*256,(k+1)*256)), + graph boundaries
// (sorted batch) + zero pooled[]. cnt/bsum pre-zeroed by hipMemsetAsync.
__global__ __launch_bounds__(256) void hist(const int* __restrict__ col,
                                            const int* __restrict__ batch,
                                            int* __restrict__ cnt,
                                            int* __restrict__ bsum,
                                            int* __restrict__ beg,
                                            int* __restrict__ endx,
                                            float* __restrict__ pooled) {
    __shared__ int histL[256];
    int tid = threadIdx.x, blk = blockIdx.x;
    histL[tid] = 0;
    __syncthreads();
    int base = blk * 4096;
#pragma unroll
    for (int k = 0; k < 16; ++k) {
        int e = base + k * 256 + tid;
        if (e < NE) {
            int c = col[e];
            atomicAdd(&cnt[c], 1);              // in-degree (50k counters)
            atomicAdd(&histL[c >> 8], 1);       // bucket count (LDS)
        }
    }
    int t = blk * 256 + tid;
    if (t < NG * HD) pooled[t] = 0.f;          // 50176 threads >= 32768
    if (t < NN) {
        int g = batch[t];
        if (t == 0 || batch[t - 1] != g) beg[g] = t;
        if (t == NN - 1 || batch[t + 1] != g) endx[g] = t + 1;
    }
    __syncthreads();
    if (tid < NBK) atomicAdd(&bsum[tid], histL[tid]);
}

// nscan: exclusive scan of cnt[NN] -> rowptr & cursor; dinv = rsqrt(cnt+1).
// Folded prefix (R21 pattern): wave 0 reduces bsum[0..blk-1] (<=196 ints)
// while waves do the intra-block scan.
__global__ __launch_bounds__(256) void nscan(const int* __restrict__ cnt,
                                             const int* __restrict__ bsum,
                                             int* __restrict__ rowptr,
                                             int* __restrict__ cursor,
                                             float* __restrict__ dinv) {
    __shared__ int ws[4];
    __shared__ int spref;
    int tid = threadIdx.x, lane = tid & 63, wid = tid >> 6;
    int i = blockIdx.x * 256 + tid;
    int v = (i < NN) ? cnt[i] : 0;
    int inc = v;
#pragma unroll
    for (int off = 1; off < 64; off <<= 1) {
        int t = __shfl_up(inc, off, 64);
        if (lane >= off) inc += t;
    }
    if (lane == 63) ws[wid] = inc;
    if (wid == 0) {                         // redundant prefix reduction
        int pref = 0;
        for (int base = 0; base < NBK; base += 64) {
            int k = base + lane;
            int bv = (k < NBK && k < blockIdx.x) ? bsum[k] : 0;
#pragma unroll
            for (int off = 32; off > 0; off >>= 1) bv += __shfl_down(bv, off, 64);
            pref += bv;                     // lane 0 holds the true sum
        }
        if (lane == 0) spref = pref;
    }
    __syncthreads();
    int woff = 0;
    for (int k = 0; k < wid; ++k) woff += ws[k];
    if (i < NN) {
        int excl = spref + woff + inc - v;
        rowptr[i] = excl;
        cursor[i] = excl;
        dinv[i] = rsqrtf((float)(v + 1));   // +1 self-loop
    }
    if (i == 0) rowptr[NN] = NE;
}

// ---------------------------------------------------------------------------
// Fused: blocks [0,GEMM_BLOCKS) do h16 = fp16(dinv * (x @ W1)) — SCALED,
// single fp16 rounding (dinv ready from nscan; wave-uniform load since r4 is
// wave-uniform); blocks [GEMM_BLOCKS, +NBL) fill esrc via global cursor
// atomics (direct CSR fill — no packed, no per-bucket rescan).
__global__ __launch_bounds__(256) void gemm1_fill(const float* __restrict__ x,
                                                  const float* __restrict__ W1,
                                                  const float* __restrict__ dinv,
                                                  __half* __restrict__ h16,
                                                  const int* __restrict__ row,
                                                  const int* __restrict__ col,
                                                  int* __restrict__ cursor,
                                                  int* __restrict__ esrc) {
    if (blockIdx.x < GEMM_BLOCKS) {
        __shared__ float Is[16][64];   // 4 KB
        int t = threadIdx.x;
        int c = t & 63, r4 = t >> 6;
        float wcol[64];                // W1 column c, L2-hot (16 KB total)
#pragma unroll
        for (int k = 0; k < 64; ++k) wcol[k] = W1[k * HD + c];
        int row0 = blockIdx.x * 16;
        float d0 = dinv[row0 + r4 + 0];     // wave-uniform (r4 const per wave)
        float d1 = dinv[row0 + r4 + 4];
        float d2 = dinv[row0 + r4 + 8];
        float d3 = dinv[row0 + r4 + 12];
        for (int i = t; i < 16 * 64; i += 256)
            Is[i >> 6][i & 63] = x[(row0 + (i >> 6)) * HD + (i & 63)];
        __syncthreads();
        float a0 = 0.f, a1 = 0.f, a2 = 0.f, a3 = 0.f;
        const float4* i0p = (const float4*)&Is[r4 + 0][0];
        const float4* i1p = (const float4*)&Is[r4 + 4][0];
        const float4* i2p = (const float4*)&Is[r4 + 8][0];
        const float4* i3p = (const float4*)&Is[r4 + 12][0];
#pragma unroll
        for (int q = 0; q < 16; ++q) {  // k = 4q..4q+3, ascending (bit-exact)
            float4 i0 = i0p[q], i1 = i1p[q], i2 = i2p[q], i3 = i3p[q];
            float w0 = wcol[4 * q + 0], w1 = wcol[4 * q + 1];
            float w2 = wcol[4 * q + 2], w3 = wcol[4 * q + 3];
            a0 += i0.x * w0; a0 += i0.y * w1; a0 += i0.z * w2; a0 += i0.w * w3;
            a1 += i1.x * w0; a1 += i1.y * w1; a1 += i1.z * w2; a1 += i1.w * w3;
            a2 += i2.x * w0; a2 += i2.y * w1; a2 += i2.z * w2; a2 += i2.w * w3;
            a3 += i3.x * w0; a3 += i3.y * w1; a3 += i3.z * w2; a3 += i3.w * w3;
        }
        h16[(row0 + r4 + 0) * HD + c] = __float2half(d0 * a0);
        h16[(row0 + r4 + 4) * HD + c] = __float2half(d1 * a1);
        h16[(row0 + r4 + 8) * HD + c] = __float2half(d2 * a2);
        h16[(row0 + r4 + 12) * HD + c] = __float2half(d3 * a3);
    } else {
        int tid = threadIdx.x, blk = blockIdx.x - GEMM_BLOCKS;
        int base = blk * 4096;
#pragma unroll
        for (int k = 0; k < 16; ++k) {
            int e = base + k * 256 + tid;
            if (e < NE) {
                int c = col[e];
                int pos = atomicAdd(&cursor[c], 1);
                esrc[pos] = row[e];
            }
        }
    }
}

// ---------------------------------------------------------------------------
// Fused gather + next-layer GEMM (R19 body + R21 load-hoist — bench-proven
// 46.5-47.5 µs, at its random-fabric roofline; see header). ONE node per
// wave (readfirstlane -> scalar esrc stream). NAMED SCALARS ONLY.
// Epilogue (POOL=false): o = dinv*(acc+self)+b, then h'next[node] =
// fp16(dinv * (relu(o) @ Wnext)) — W column in VGPRs, row broadcast via
// per-wave LDS + ds_read_b128. Epilogue (POOL=true): pool atomics.
template <bool POOL>
__global__ __launch_bounds__(256) void gather_fx(const __half* __restrict__ hp,
                                                 const int* __restrict__ rowptr,
                                                 const int* __restrict__ esrc,
                                                 const float* __restrict__ dinv,
                                                 const float* __restrict__ b,
                                                 const float* __restrict__ Wnext,
                                                 __half* __restrict__ hnext,
                                                 const int* __restrict__ batch,
                                                 float* __restrict__ pooled) {
    __shared__ float rowbuf[4][64];             // 1 KB, per-wave slices
    int tid = threadIdx.x, lane = tid & 63, wid = tid >> 6;
    int p = lane >> 5, c = lane & 31;           // edge-of-pair, half2 channel
    int node = __builtin_amdgcn_readfirstlane(blockIdx.x * 4 + wid);
    const __half2* hv = (const __half2*)hp;

    // Independent loads FIRST (R21): overlap the rowptr->esrc scalar chain.
    float di = dinv[node];                      // wave-uniform scalar load
    float2 self = __half22float2(hv[node * 32 + c]);   // pre-scaled h'
    float2 bb = ((const float2*)b)[c];

    float wcol[POOL ? 1 : 64];                  // W column for this lane
    if (!POOL) {
#pragma unroll
        for (int k = 0; k < 64; ++k) wcol[k] = Wnext[k * HD + lane];  // L2-hot
    }

    int s = rowptr[node], e = rowptr[node + 1];     // scalar loads
    float2 acc = {0.f, 0.f};
    int j = s;
    for (; j + 8 <= e; j += 8) {                // unmasked full batches
        int t0 = esrc[j + 0], t1 = esrc[j + 1], t2 = esrc[j + 2], t3 = esrc[j + 3];
        int t4 = esrc[j + 4], t5 = esrc[j + 5], t6 = esrc[j + 6], t7 = esrc[j + 7];
        int a0 = p ? t1 : t0;
        int a1 = p ? t3 : t2;
        int a2 = p ? t5 : t4;
        int a3 = p ? t7 : t6;
        float2 f0 = __half22float2(hv[a0 * 32 + c]);
        float2 f1 = __half22float2(hv[a1 * 32 + c]);
        float2 f2 = __half22float2(hv[a2 * 32 + c]);
        float2 f3 = __half22float2(hv[a3 * 32 + c]);
        acc.x += (f0.x + f1.x) + (f2.x + f3.x);
        acc.y += (f0.y + f1.y) + (f2.y + f3.y);
    }
    if (j < e) {                                // ONE masked batch (rem 1..7)
        // overrun reads stay in allocated memory (esrc padded +64); &0xFFFF
        // keeps row index in-bounds; invalid lanes clamp to t0 (real edge,
        // j < e) and are zero-multiplied.
        int t0 = esrc[j + 0] & 0xFFFF, t1 = esrc[j + 1] & 0xFFFF;
        int t2 = esrc[j + 2] & 0xFFFF, t3 = esrc[j + 3] & 0xFFFF;
        int t4 = esrc[j + 4] & 0xFFFF, t5 = esrc[j + 5] & 0xFFFF;
        int t6 = esrc[j + 6] & 0xFFFF, t7 = esrc[j + 7] & 0xFFFF;
        int i0 = j + p, i1 = j + 2 + p, i2 = j + 4 + p, i3 = j + 6 + p;
        int a0 = p ? t1 : t0;
        int a1 = p ? t3 : t2;
        int a2 = p ? t5 : t4;
        int a3 = p ? t7 : t6;
        a0 = (i0 < e) ? a0 : t0;
        a1 = (i1 < e) ? a1 : t0;
        a2 = (i2 < e) ? a2 : t0;
        a3 = (i3 < e) ? a3 : t0;
        float m0 = (i0 < e) ? 1.f : 0.f;
        float m1 = (i1 < e) ? 1.f : 0.f;
        float m2 = (i2 < e) ? 1.f : 0.f;
        float m3 = (i3 < e) ? 1.f : 0.f;
        float2 f0 = __half22float2(hv[a0 * 32 + c]);
        float2 f1 = __half22float2(hv[a1 * 32 + c]);
        float2 f2 = __half22float2(hv[a2 * 32 + c]);
        float2 f3 = __half22float2(hv[a3 * 32 + c]);
        acc.x += m0 * f0.x + m1 * f1.x + m2 * f2.x + m3 * f3.x;
        acc.y += m0 * f0.y + m1 * f1.y + m2 * f2.y + m3 * f3.y;
    }
    // combine the two edge-pair partials (lane L ^ 32 holds same channel)
    acc.x += __shfl_xor(acc.x, 32, 64);
    acc.y += __shfl_xor(acc.y, 32, 64);

    if (POOL) {
        if (p == 0) {
            float vx = di * (acc.x + self.x) + bb.x;
            float vy = di * (acc.y + self.y) + bb.y;
            int g = batch[node];
            atomicAdd(&pooled[g * HD + 2 * c], vx);
            atomicAdd(&pooled[g * HD + 2 * c + 1], vy);
        }
    } else {
        if (p == 0) {                           // o = dinv*(acc+self)+b; relu
            rowbuf[wid][2 * c]     = fmaxf(di * (acc.x + self.x) + bb.x, 0.f);
            rowbuf[wid][2 * c + 1] = fmaxf(di * (acc.y + self.y) + bb.y, 0.f);
        }
        // same-wave LDS write->read; compiler inserts lgkmcnt wait. No cross-
        // wave hazard: rowbuf slice is private to this wave.
        float outc = 0.f;
        const float4* rb4 = (const float4*)&rowbuf[wid][0];
#pragma unroll
        for (int jj = 0; jj < 16; ++jj) {       // 16 broadcast b128 reads
            float4 r = rb4[jj];
            outc += r.x * wcol[4 * jj + 0] + r.y * wcol[4 * jj + 1]
                  + r.z * wcol[4 * jj + 2] + r.w * wcol[4 * jj + 3];
        }
        hnext[(size_t)node * HD + lane] = __float2half(di * outc);
    }
}

// out[g] = (pooled[g,:]/max(cnt,1)) . lin_W + lin_b   — one wave per graph
__global__ __launch_bounds__(64) void final_kernel(const float* __restrict__ pooled,
                                                   const int* __restrict__ beg,
                                                   const int* __restrict__ endx,
                                                   const float* __restrict__ lin_W,
                                                   const float* __restrict__ lin_b,
                                                   float* __restrict__ out) {
    int g = blockIdx.x, d = threadIdx.x;
    float cnt = (float)(endx[g] - beg[g]);
    float v = pooled[g * HD + d] / fmaxf(cnt, 1.f) * lin_W[d];
#pragma unroll
    for (int off = 32; off > 0; off >>= 1) v += __shfl_down(v, off, 64);
    if (d == 0) out[g] = v + lin_b[0];
}

// ---------------------------------------------------------------------------
extern "C" void kernel_launch(void* const* d_in, const int* in_sizes, int n_in,
                              void* d_out, int out_size, void* d_ws, size_t ws_size,
                              hipStream_t stream) {
    const float* x     = (const float*)d_in[0];
    const float* W1    = (const float*)d_in[1];
    const float* b1    = (const float*)d_in[2];
    const float* W2    = (const float*)d_in[3];
    const float* b2    = (const float*)d_in[4];
    const float* W3    = (const float*)d_in[5];
    const float* b3    = (const float*)d_in[6];
    const float* lin_W = (const float*)d_in[7];
    const float* lin_b = (const float*)d_in[8];
    const int* edge_index = (const int*)d_in[9];   // [2, NE]: row then col
    const int* batch      = (const int*)d_in[10];
    const int* row = edge_index;
    const int* col = edge_index + NE;
    float* out = (float*)d_out;

    // workspace layout (4B units):
    // [h16a NN*HD half][h16b NN*HD half][esrc NE+64]
    // [cnt NN][bsum 256]  <- contiguous, one memset
    // [cursor NN][rowptr NN+2][dinv NN][pooled NG*HD][beg NG][endx NG]
    __half*   h16a      = (__half*)d_ws;
    __half*   h16b      = h16a + (size_t)NN * HD;
    int*      esrc      = (int*)(h16b + (size_t)NN * HD);
    int*      cnt       = esrc + NE + 64;
    int*      bsum      = cnt + NN;
    int*      cursor    = bsum + 256;
    int*      rowptr    = cursor + NN;
    float*    dinv      = (float*)(rowptr + NN + 2);
    float*    pooled    = (float*)(dinv + NN);
    int*      beg       = (int*)(pooled + NG * HD);
    int*      endx      = beg + NG;

    // zero cnt+bsum (contiguous) -> hist -> scan -> gemm1+fill -> gathers
    hipMemsetAsync(cnt, 0, (size_t)(NN + 256) * sizeof(int), stream);
    hist<<<NBL, 256, 0, stream>>>(col, batch, cnt, bsum, beg, endx, pooled);
    nscan<<<NBK, 256, 0, stream>>>(cnt, bsum, rowptr, cursor, dinv);
    gemm1_fill<<<GEMM_BLOCKS + NBL, 256, 0, stream>>>(x, W1, dinv, h16a, row,
                                                      col, cursor, esrc);

    const int GB = NN / 4;  // gather blocks: 4 nodes (waves) each

    // Layer 1 aggregate + fused GEMM2: h16a(=h1') -> h16b(=h2')
    gather_fx<false><<<GB, 256, 0, stream>>>(h16a, rowptr, esrc, dinv, b1, W2,
                                             h16b, batch, pooled);
    // Layer 2 aggregate + fused GEMM3: h16b(=h2') -> h16a(=h3')
    gather_fx<false><<<GB, 256, 0, stream>>>(h16b, rowptr, esrc, dinv, b2, W3,
                                             h16a, batch, pooled);
    // Layer 3 aggregate -> pooled (fused)
    gather_fx<true><<<GB, 256, 0, stream>>>(h16a, rowptr, esrc, dinv, b3, nullptr,
                                            nullptr, batch, pooled);

    final_kernel<<<NG, 64, 0, stream>>>(pooled, beg, endx, lin_W, lin_b, out);
}

// Round 6
// 275.931 us; speedup vs baseline: 1.0754x; 1.0754x over previous
//
#include <hip/hip_runtime.h>
#include <hip/hip_fp16.h>

// Problem constants (fixed by the reference file)
#define NN 50000     // nodes
#define NE 800000    // edges
#define HD 64        // feature dim (in and hidden)
#define NG 512       // graphs
#define NBK 196      // node buckets: node >> 8, max 49999>>8 = 195
#define NBL 196      // edge blocks of 4096: ceil(NE/4096)
#define M_CNT (NBK * NBL)       // 38416 bucket-block counts
#define NBS 151                 // scan blocks: ceil(M_CNT/256)
#define GEMM_BLOCKS 3125        // NN/16

// Math: with h' = dinv*h (fp16):
//   o[c]   = dinv[c] * (sum_src h'[src] + h'[c]) + b          (layer output)
//   h'next = dinv * (relu(o) @ Wnext)                          (fused GEMM)
// R25 hybrid: R23's bucketed two-phase CSR fill (packed -> per-bucket
// L2-resident fill; coalesced segment writes) + R24's validated early
// per-node degree (global cnt atomics, absmax 0.0). This deletes
// csr_build's histogram+scan AND the 12.8 MB h16 rescale pass: gemm1
// writes SCALED h16 (single fp16 rounding), rowptr comes from a 196-block
// node-scan folded into the gemm1_scatter dispatch (prefix = counts_ex
// [b*NBL], no extra launch). dinv array deleted — rsqrt(cnt+1) inline.
// R24 POST-MORTEM (do not revisit): direct cursor-atomic esrc fill ->
// 60.5 MB write amplification (random 4B stores + atomic line ping-pong
// across 8 non-coherent XCD L2s), gemm1_fill 60.9 µs. Bucketed fill wins.
//
// Gather body is R15/R21's proven shape (46.5-47.5 µs; ~12 variants tried):
// node-per-wave, scalar esrc stream, unmasked 8-edge batches + ONE masked
// batch, independent loads hoisted. DO NOT TOUCH:
//  - R20: int t[32] preload -> scratch spill (+25.6MB writes), 2x slower.
//  - R22: h2x2 8B-aggregate loads -> 8B/thread scratch spill, 2x slower.
//    FETCH 35MB ~= compulsory fabric floor -> gather at its random-access
//    roofline (HBM 17%, VALU 21%, occ 65%: latency floor, robust to shape).
// R23: gemm1 GEMM half: W column in VGPRs + wave-uniform broadcast float4
// LDS reads (was LDS-issue-bound). k-ascending FMA order.

// ---------------------------------------------------------------------------
// Pass A: per-(block,bucket) edge counts via LDS histogram + per-node
// in-degree via global atomics (R24-validated) + graph boundaries (sorted
// batch) + zero pooled[]. cnt pre-zeroed by hipMemsetAsync.
__global__ __launch_bounds__(256) void bucket_count(const int* __restrict__ col,
                                                    const int* __restrict__ batch,
                                                    int* __restrict__ cnt,
                                                    int* __restrict__ counts,
                                                    int* __restrict__ beg,
                                                    int* __restrict__ endx,
                                                    float* __restrict__ pooled) {
    __shared__ int hist[256];
    int tid = threadIdx.x, blk = blockIdx.x;
    hist[tid] = 0;
    __syncthreads();
    int base = blk * 4096;
#pragma unroll
    for (int k = 0; k < 16; ++k) {
        int e = base + k * 256 + tid;
        if (e < NE) {
            int c = col[e];
            atomicAdd(&cnt[c], 1);              // per-node in-degree
            atomicAdd(&hist[c >> 8], 1);        // per-bucket count (LDS)
        }
    }
    int t = blk * 256 + tid;
    if (t < NG * HD) pooled[t] = 0.f;          // 50176 threads >= 32768
    if (t < NN) {
        int g = batch[t];
        if (t == 0 || batch[t - 1] != g) beg[g] = t;
        if (t == NN - 1 || batch[t + 1] != g) endx[g] = t + 1;
    }
    __syncthreads();
    if (tid < NBK) counts[tid * NBL + blk] = hist[tid];  // bucket-major
}

// ---- 2-stage exclusive scan over counts[M_CNT] ----------------------------
__global__ __launch_bounds__(256) void block_reduce(const int* __restrict__ src,
                                                    int* __restrict__ bsum) {
    __shared__ int ws[4];
    int tid = threadIdx.x, lane = tid & 63, wid = tid >> 6;
    int i = blockIdx.x * 256 + tid;
    int v = (i < M_CNT) ? src[i] : 0;
#pragma unroll
    for (int off = 32; off > 0; off >>= 1) v += __shfl_down(v, off, 64);
    if (lane == 0) ws[wid] = v;
    __syncthreads();
    if (tid == 0) bsum[blockIdx.x] = ws[0] + ws[1] + ws[2] + ws[3];
}

// block_scan (R21): computes its own bsum-prefix (reduction over raw
// per-block sums). Wave 0 reduces bsum[0..blk-1] while others scan.
__global__ __launch_bounds__(256) void block_scan(const int* __restrict__ src,
                                                  const int* __restrict__ bsum,
                                                  int* __restrict__ dst) {
    __shared__ int ws[4];
    __shared__ int spref;
    int tid = threadIdx.x, lane = tid & 63, wid = tid >> 6;
    int i = blockIdx.x * 256 + tid;
    int v = (i < M_CNT) ? src[i] : 0;
    int inc = v;
#pragma unroll
    for (int off = 1; off < 64; off <<= 1) {
        int t = __shfl_up(inc, off, 64);
        if (lane >= off) inc += t;
    }
    if (lane == 63) ws[wid] = inc;
    if (wid == 0) {                         // redundant prefix reduction
        int pref = 0;
        for (int base = 0; base < NBS; base += 64) {
            int k = base + lane;
            int bv = (k < NBS && k < blockIdx.x) ? bsum[k] : 0;
#pragma unroll
            for (int off = 32; off > 0; off >>= 1) bv += __shfl_down(bv, off, 64);
            pref += bv;                     // lane 0 holds the true sum
        }
        if (lane == 0) spref = pref;
    }
    __syncthreads();
    int woff = 0;
    for (int k = 0; k < wid; ++k) woff += ws[k];
    if (i < M_CNT) dst[i] = spref + woff + inc - v;
}

// ---------------------------------------------------------------------------
// Fused 3-range dispatch:
//  [0, GEMM_BLOCKS):          h16 = fp16(dinv * (x @ W1)) — SCALED, single
//                             rounding; dinv inline from cnt (wave-uniform).
//  [GEMM_BLOCKS, +NBL):       scatter edges into packed[] (LDS cursors).
//  [GEMM_BLOCKS+NBL, +NBK):   node-scan: rowptr from cnt, prefix =
//                             counts_ex[b*NBL] (edges in buckets < b).
// All three ranges are mutually independent (no intra-grid ordering needed).
__global__ __launch_bounds__(256) void gemm1_scatter(const float* __restrict__ x,
                                                     const float* __restrict__ W1,
                                                     const int* __restrict__ cnt,
                                                     __half* __restrict__ h16,
                                                     const int* __restrict__ row,
                                                     const int* __restrict__ col,
                                                     const int* __restrict__ counts_ex,
                                                     unsigned* __restrict__ packed,
                                                     int* __restrict__ rowptr) {
    if (blockIdx.x < GEMM_BLOCKS) {
        __shared__ float Is[16][64];   // 4 KB
        int t = threadIdx.x;
        int c = t & 63, r4 = t >> 6;
        float wcol[64];                // W1 column c, L2-hot (16 KB total)
#pragma unroll
        for (int k = 0; k < 64; ++k) wcol[k] = W1[k * HD + c];
        int row0 = blockIdx.x * 16;
        // wave-uniform scalar loads + rsqrt (R24-validated numerics)
        float d0 = rsqrtf((float)(cnt[row0 + r4 + 0] + 1));
        float d1 = rsqrtf((float)(cnt[row0 + r4 + 4] + 1));
        float d2 = rsqrtf((float)(cnt[row0 + r4 + 8] + 1));
        float d3 = rsqrtf((float)(cnt[row0 + r4 + 12] + 1));
        for (int i = t; i < 16 * 64; i += 256)
            Is[i >> 6][i & 63] = x[(row0 + (i >> 6)) * HD + (i & 63)];
        __syncthreads();
        float a0 = 0.f, a1 = 0.f, a2 = 0.f, a3 = 0.f;
        const float4* i0p = (const float4*)&Is[r4 + 0][0];
        const float4* i1p = (const float4*)&Is[r4 + 4][0];
        const float4* i2p = (const float4*)&Is[r4 + 8][0];
        const float4* i3p = (const float4*)&Is[r4 + 12][0];
#pragma unroll
        for (int q = 0; q < 16; ++q) {  // k = 4q..4q+3, ascending (bit-exact)
            float4 i0 = i0p[q], i1 = i1p[q], i2 = i2p[q], i3 = i3p[q];
            float w0 = wcol[4 * q + 0], w1 = wcol[4 * q + 1];
            float w2 = wcol[4 * q + 2], w3 = wcol[4 * q + 3];
            a0 += i0.x * w0; a0 += i0.y * w1; a0 += i0.z * w2; a0 += i0.w * w3;
            a1 += i1.x * w0; a1 += i1.y * w1; a1 += i1.z * w2; a1 += i1.w * w3;
            a2 += i2.x * w0; a2 += i2.y * w1; a2 += i2.z * w2; a2 += i2.w * w3;
            a3 += i3.x * w0; a3 += i3.y * w1; a3 += i3.z * w2; a3 += i3.w * w3;
        }
        h16[(row0 + r4 + 0) * HD + c] = __float2half(d0 * a0);
        h16[(row0 + r4 + 4) * HD + c] = __float2half(d1 * a1);
        h16[(row0 + r4 + 8) * HD + c] = __float2half(d2 * a2);
        h16[(row0 + r4 + 12) * HD + c] = __float2half(d3 * a3);
    } else if (blockIdx.x < GEMM_BLOCKS + NBL) {
        __shared__ int cur[256];
        int tid = threadIdx.x, blk = blockIdx.x - GEMM_BLOCKS;
        cur[tid] = 0;
        __syncthreads();
        int base = blk * 4096;
#pragma unroll
        for (int k = 0; k < 16; ++k) {
            int e = base + k * 256 + tid;
            if (e < NE) {
                int c = col[e], r = row[e];
                int b = c >> 8;
                int lpos = atomicAdd(&cur[b], 1);
                int pos = counts_ex[b * NBL + blk] + lpos;
                packed[pos] = (unsigned)r | ((unsigned)(c & 255) << 16);
            }
        }
    } else {
        // node-scan: rowptr[node] = counts_ex[b*NBL] + excl-scan(cnt) in b
        __shared__ int ws[4];
        int b = blockIdx.x - (GEMM_BLOCKS + NBL);
        int tid = threadIdx.x, lane = tid & 63, wid = tid >> 6;
        int node = b * 256 + tid;
        int v = (node < NN) ? cnt[node] : 0;
        int inc = v;
#pragma unroll
        for (int off = 1; off < 64; off <<= 1) {
            int t = __shfl_up(inc, off, 64);
            if (lane >= off) inc += t;
        }
        if (lane == 63) ws[wid] = inc;
        __syncthreads();
        int woff = 0;
        for (int k = 0; k < wid; ++k) woff += ws[k];
        int s0 = counts_ex[b * NBL];        // edges in buckets < b
        if (node <= NN) rowptr[node] = s0 + woff + inc - v;
        // node==NN (b=195,tid=80): v=0, prefix = bucket total -> rowptr[NN]=NE
    }
}

// ---------------------------------------------------------------------------
// csr_fill: per 256-col bucket, place edges: slot = rowptr[col] + LDS cursor.
// Pure fill — histogram/scan/rescale deleted (R25). Segment [s,e) of packed
// is L2-resident per bucket; esrc writes land in one contiguous 16KB region.
__global__ __launch_bounds__(256) void csr_fill(const unsigned* __restrict__ packed,
                                                const int* __restrict__ counts_ex,
                                                const int* __restrict__ rowptr,
                                                int* __restrict__ esrc) {
    __shared__ int lrp[256];
    __shared__ int cur[256];
    int bkt = blockIdx.x, tid = threadIdx.x;
    int s = counts_ex[bkt * NBL];
    int e = (bkt == NBK - 1) ? NE : counts_ex[(bkt + 1) * NBL];
    int node = bkt * 256 + tid;
    lrp[tid] = (node < NN) ? rowptr[node] : 0;
    cur[tid] = 0;
    __syncthreads();
    for (int j = s + tid; j < e; j += 256) {
        unsigned p = packed[j];
        int lc = (p >> 16) & 255;
        int slot = lrp[lc] + atomicAdd(&cur[lc], 1);
        esrc[slot] = (int)(p & 0xFFFF);          // NN < 65536
    }
}

// ---------------------------------------------------------------------------
// Fused gather + next-layer GEMM (R19 body + R21 load-hoist — bench-proven
// 46.5-47.5 µs floor). ONE node per wave (readfirstlane -> scalar esrc
// stream). NAMED SCALARS ONLY (R20/R22 spill lessons). dinv computed inline
// from cnt (one wave-uniform scalar load + rsqrt; R24-validated).
// Epilogue (POOL=false): o = dinv*(acc+self)+b, then h'next[node] =
// fp16(dinv * (relu(o) @ Wnext)) — W column in VGPRs, row broadcast via
// per-wave LDS + ds_read_b128. Epilogue (POOL=true): pool atomics.
template <bool POOL>
__global__ __launch_bounds__(256) void gather_fx(const __half* __restrict__ hp,
                                                 const int* __restrict__ rowptr,
                                                 const int* __restrict__ esrc,
                                                 const int* __restrict__ cnt,
                                                 const float* __restrict__ b,
                                                 const float* __restrict__ Wnext,
                                                 __half* __restrict__ hnext,
                                                 const int* __restrict__ batch,
                                                 float* __restrict__ pooled) {
    __shared__ float rowbuf[4][64];             // 1 KB, per-wave slices
    int tid = threadIdx.x, lane = tid & 63, wid = tid >> 6;
    int p = lane >> 5, c = lane & 31;           // edge-of-pair, half2 channel
    int node = __builtin_amdgcn_readfirstlane(blockIdx.x * 4 + wid);
    const __half2* hv = (const __half2*)hp;

    // Independent loads FIRST (R21): overlap the rowptr->esrc scalar chain.
    float di = rsqrtf((float)(cnt[node] + 1)); // wave-uniform load + rsqrt
    float2 self = __half22float2(hv[node * 32 + c]);   // pre-scaled h'
    float2 bb = ((const float2*)b)[c];

    float wcol[POOL ? 1 : 64];                  // W column for this lane
    if (!POOL) {
#pragma unroll
        for (int k = 0; k < 64; ++k) wcol[k] = Wnext[k * HD + lane];  // L2-hot
    }

    int s = rowptr[node], e = rowptr[node + 1];     // scalar loads
    float2 acc = {0.f, 0.f};
    int j = s;
    for (; j + 8 <= e; j += 8) {                // unmasked full batches
        int t0 = esrc[j + 0], t1 = esrc[j + 1], t2 = esrc[j + 2], t3 = esrc[j + 3];
        int t4 = esrc[j + 4], t5 = esrc[j + 5], t6 = esrc[j + 6], t7 = esrc[j + 7];
        int a0 = p ? t1 : t0;
        int a1 = p ? t3 : t2;
        int a2 = p ? t5 : t4;
        int a3 = p ? t7 : t6;
        float2 f0 = __half22float2(hv[a0 * 32 + c]);
        float2 f1 = __half22float2(hv[a1 * 32 + c]);
        float2 f2 = __half22float2(hv[a2 * 32 + c]);
        float2 f3 = __half22float2(hv[a3 * 32 + c]);
        acc.x += (f0.x + f1.x) + (f2.x + f3.x);
        acc.y += (f0.y + f1.y) + (f2.y + f3.y);
    }
    if (j < e) {                                // ONE masked batch (rem 1..7)
        // overrun reads stay in allocated memory (esrc padded +64); &0xFFFF
        // bounds any garbage; invalid lanes clamp to t0 (real edge, j < e)
        // and are zero-multiplied — garbage never reaches a gather address.
        int t0 = esrc[j + 0] & 0xFFFF, t1 = esrc[j + 1] & 0xFFFF;
        int t2 = esrc[j + 2] & 0xFFFF, t3 = esrc[j + 3] & 0xFFFF;
        int t4 = esrc[j + 4] & 0xFFFF, t5 = esrc[j + 5] & 0xFFFF;
        int t6 = esrc[j + 6] & 0xFFFF, t7 = esrc[j + 7] & 0xFFFF;
        int i0 = j + p, i1 = j + 2 + p, i2 = j + 4 + p, i3 = j + 6 + p;
        int a0 = p ? t1 : t0;
        int a1 = p ? t3 : t2;
        int a2 = p ? t5 : t4;
        int a3 = p ? t7 : t6;
        a0 = (i0 < e) ? a0 : t0;
        a1 = (i1 < e) ? a1 : t0;
        a2 = (i2 < e) ? a2 : t0;
        a3 = (i3 < e) ? a3 : t0;
        float m0 = (i0 < e) ? 1.f : 0.f;
        float m1 = (i1 < e) ? 1.f : 0.f;
        float m2 = (i2 < e) ? 1.f : 0.f;
        float m3 = (i3 < e) ? 1.f : 0.f;
        float2 f0 = __half22float2(hv[a0 * 32 + c]);
        float2 f1 = __half22float2(hv[a1 * 32 + c]);
        float2 f2 = __half22float2(hv[a2 * 32 + c]);
        float2 f3 = __half22float2(hv[a3 * 32 + c]);
        acc.x += m0 * f0.x + m1 * f1.x + m2 * f2.x + m3 * f3.x;
        acc.y += m0 * f0.y + m1 * f1.y + m2 * f2.y + m3 * f3.y;
    }
    // combine the two edge-pair partials (lane L ^ 32 holds same channel)
    acc.x += __shfl_xor(acc.x, 32, 64);
    acc.y += __shfl_xor(acc.y, 32, 64);

    if (POOL) {
        if (p == 0) {
            float vx = di * (acc.x + self.x) + bb.x;
            float vy = di * (acc.y + self.y) + bb.y;
            int g = batch[node];
            atomicAdd(&pooled[g * HD + 2 * c], vx);
            atomicAdd(&pooled[g * HD + 2 * c + 1], vy);
        }
    } else {
        if (p == 0) {                           // o = dinv*(acc+self)+b; relu
            rowbuf[wid][2 * c]     = fmaxf(di * (acc.x + self.x) + bb.x, 0.f);
            rowbuf[wid][2 * c + 1] = fmaxf(di * (acc.y + self.y) + bb.y, 0.f);
        }
        // same-wave LDS write->read; compiler inserts lgkmcnt wait. No cross-
        // wave hazard: rowbuf slice is private to this wave.
        float outc = 0.f;
        const float4* rb4 = (const float4*)&rowbuf[wid][0];
#pragma unroll
        for (int jj = 0; jj < 16; ++jj) {       // 16 broadcast b128 reads
            float4 r = rb4[jj];
            outc += r.x * wcol[4 * jj + 0] + r.y * wcol[4 * jj + 1]
                  + r.z * wcol[4 * jj + 2] + r.w * wcol[4 * jj + 3];
        }
        hnext[(size_t)node * HD + lane] = __float2half(di * outc);
    }
}

// out[g] = (pooled[g,:]/max(cnt,1)) . lin_W + lin_b   — one wave per graph
__global__ __launch_bounds__(64) void final_kernel(const float* __restrict__ pooled,
                                                   const int* __restrict__ beg,
                                                   const int* __restrict__ endx,
                                                   const float* __restrict__ lin_W,
                                                   const float* __restrict__ lin_b,
                                                   float* __restrict__ out) {
    int g = blockIdx.x, d = threadIdx.x;
    float cnt = (float)(endx[g] - beg[g]);
    float v = pooled[g * HD + d] / fmaxf(cnt, 1.f) * lin_W[d];
#pragma unroll
    for (int off = 32; off > 0; off >>= 1) v += __shfl_down(v, off, 64);
    if (d == 0) out[g] = v + lin_b[0];
}

// ---------------------------------------------------------------------------
extern "C" void kernel_launch(void* const* d_in, const int* in_sizes, int n_in,
                              void* d_out, int out_size, void* d_ws, size_t ws_size,
                              hipStream_t stream) {
    const float* x     = (const float*)d_in[0];
    const float* W1    = (const float*)d_in[1];
    const float* b1    = (const float*)d_in[2];
    const float* W2    = (const float*)d_in[3];
    const float* b2    = (const float*)d_in[4];
    const float* W3    = (const float*)d_in[5];
    const float* b3    = (const float*)d_in[6];
    const float* lin_W = (const float*)d_in[7];
    const float* lin_b = (const float*)d_in[8];
    const int* edge_index = (const int*)d_in[9];   // [2, NE]: row then col
    const int* batch      = (const int*)d_in[10];
    const int* row = edge_index;
    const int* col = edge_index + NE;
    float* out = (float*)d_out;

    // workspace layout (4B units):
    // [h16a NN*HD half][h16b NN*HD half][esrc NE+64][packed NE]
    // [counts M][counts_ex M][cnt NN][rowptr NN+2]
    // [bsum 256][pooled NG*HD][beg NG][endx NG]      total ~20 MB
    __half*   h16a      = (__half*)d_ws;
    __half*   h16b      = h16a + (size_t)NN * HD;
    int*      esrc      = (int*)(h16b + (size_t)NN * HD);
    unsigned* packed    = (unsigned*)(esrc + NE + 64);
    int*      counts    = (int*)(packed + NE);
    int*      counts_ex = counts + M_CNT;
    int*      cnt       = counts_ex + M_CNT;
    int*      rowptr    = cnt + NN;
    int*      bsum      = rowptr + NN + 2;
    float*    pooled    = (float*)(bsum + 256);
    int*      beg       = (int*)(pooled + NG * HD);
    int*      endx      = beg + NG;

    // zero cnt -> count(+degree) -> reduce -> scan
    //  -> {gemm1(scaled) || scatter || node-scan} -> fill -> gathers -> final
    hipMemsetAsync(cnt, 0, (size_t)NN * sizeof(int), stream);
    bucket_count<<<NBL, 256, 0, stream>>>(col, batch, cnt, counts, beg, endx,
                                          pooled);
    block_reduce<<<NBS, 256, 0, stream>>>(counts, bsum);
    block_scan<<<NBS, 256, 0, stream>>>(counts, bsum, counts_ex);
    gemm1_scatter<<<GEMM_BLOCKS + NBL + NBK, 256, 0, stream>>>(
        x, W1, cnt, h16a, row, col, counts_ex, packed, rowptr);
    csr_fill<<<NBK, 256, 0, stream>>>(packed, counts_ex, rowptr, esrc);

    const int GB = NN / 4;  // gather blocks: 4 nodes (waves) each

    // Layer 1 aggregate + fused GEMM2: h16a(=h1') -> h16b(=h2')
    gather_fx<false><<<GB, 256, 0, stream>>>(h16a, rowptr, esrc, cnt, b1, W2,
                                             h16b, batch, pooled);
    // Layer 2 aggregate + fused GEMM3: h16b(=h2') -> h16a(=h3')
    gather_fx<false><<<GB, 256, 0, stream>>>(h16b, rowptr, esrc, cnt, b2, W3,
                                             h16a, batch, pooled);
    // Layer 3 aggregate -> pooled (fused)
    gather_fx<true><<<GB, 256, 0, stream>>>(h16a, rowptr, esrc, cnt, b3, nullptr,
                                            nullptr, batch, pooled);

    final_kernel<<<NG, 64, 0, stream>>>(pooled, beg, endx, lin_W, lin_b, out);
}